// Round 3
// baseline (308.328 us; speedup 1.0000x reference)
//
#include <hip/hip_runtime.h>
#include <stdint.h>

// ---------------------------------------------------------------------------
// MultiHeadedAttention: B=8, N=1024, E=512, H=8, D_K=64
// bf16 MFMA pipeline. Round 6: kt-split occupancy (32 q-rows/wave, waves
// split the 8 K-tiles 4+4, partials merged via one LDS round-trip) with the
// spill fix: plain __launch_bounds__(256) so the allocator gets the full
// 128-VGPR budget (the (256,4) hint of round 5 forced a 64-VGPR cap and
// ~92 MB of scratch spill traffic). Codes load kept AFTER QK^T to minimize
// live registers across the MFMA block.
// ---------------------------------------------------------------------------

typedef __attribute__((ext_vector_type(8))) short short8;
typedef __attribute__((ext_vector_type(4))) float floatx4;

#define MFMA16(a, b, c) __builtin_amdgcn_mfma_f32_16x16x32_bf16((a), (b), (c), 0, 0, 0)

static __device__ __forceinline__ unsigned short f2bf(float f) {
  union { float f; unsigned u; } v; v.f = f;
  unsigned r = v.u + 0x7fffu + ((v.u >> 16) & 1u);   // RNE
  return (unsigned short)(r >> 16);
}

// async global->LDS 16B/lane. LDS dest is wave-uniform base + lane*16 (m104).
static __device__ __forceinline__ void gload_lds16(const void* g, void* l) {
  __builtin_amdgcn_global_load_lds((const __attribute__((address_space(1))) unsigned int*)g,
                                   (__attribute__((address_space(3))) unsigned int*)l,
                                   16, 0, 0);
}
// chunk swizzle for unpadded 32-elem-wide bf16 LDS tiles (GEMM staging).
static __device__ __forceinline__ int xsw(int row) { return (row & 3) ^ ((row >> 2) & 3); }

// ---------------- weight cast fp32 -> bf16 (all 4 at once) ----------------
__global__ void wcast_kernel(const float* __restrict__ Wq, const float* __restrict__ Wk,
                             const float* __restrict__ Wv, const float* __restrict__ Wo,
                             unsigned short* __restrict__ o0, unsigned short* __restrict__ o1,
                             unsigned short* __restrict__ o2, unsigned short* __restrict__ o3) {
  int i = blockIdx.x * blockDim.x + threadIdx.x;   // 0..262143
  int w = i >> 16, loc = i & 65535;
  const float* s = (w == 0) ? Wq : (w == 1) ? Wk : (w == 2) ? Wv : Wo;
  unsigned short* d = (w == 0) ? o0 : (w == 1) ? o1 : (w == 2) ? o2 : o3;
  float4 v = ((const float4*)s)[loc];
  ushort4 o;
  o.x = f2bf(v.x); o.y = f2bf(v.y); o.z = f2bf(v.z); o.w = f2bf(v.w);
  ((ushort4*)d)[loc] = o;
}

// ---------------- dist+mask -> permuted code bytes ----------------
// allowed(h) <=> h >= code (DIST_BAR ascending). 0 on row/col 0; 9 if mask==0.
// Output layout matches the attn exp-epilogue exactly:
//   codesP[ (((b*32+rg)*8 + kt)*64 + lane)*64 + st*32 + ci*4 + r ]
// where row = rg*32 + st*16 + q*4 + r, col = kt*128 + ci*16 + c, lane = q*16+c.
// Each attn lane then reads its 64 bytes/kt as 4 coalesced dwordx4.
__global__ void codes_kernel(const float* __restrict__ dist, const int* __restrict__ mask,
                             unsigned char* __restrict__ codesP) {
  int t = blockIdx.x * blockDim.x + threadIdx.x;   // over B*N*N/4
  int flat = t << 2;
  int b = flat >> 20;
  int rem = flat & ((1 << 20) - 1);
  int row = rem >> 10;
  int col0 = rem & 1023;
  float4 d4 = ((const float4*)dist)[t];
  int4 m4 = ((const int4*)mask)[t];
  float dv[4] = {d4.x, d4.y, d4.z, d4.w};
  int mv[4] = {m4.x, m4.y, m4.z, m4.w};
  int rg = row >> 5;
  int st = (row >> 4) & 1;
  int qq = (row >> 2) & 3;
  int r = row & 3;
  size_t rowbase = (size_t)(b * 32 + rg) * 32768;   // *8 kt *4096
  int sub = st * 32 + r;
#pragma unroll
  for (int u = 0; u < 4; u++) {
    int col = col0 + u;
    float d = dv[u];
    int hmin = (d >= 0.2f) + (d >= 0.3f) + (d >= 0.4f) + (d >= 0.5f) +
               (d >= 0.6f) + (d >= 0.7f) + (d >= 0.8f) + (d >= 0.9f);
    unsigned char cc = (unsigned char)hmin;
    if (row == 0 || col == 0) cc = 0;
    if (mv[u] == 0) cc = 9;
    int kt = col >> 7, ci = (col >> 4) & 7, c = col & 15;
    int lane = qq * 16 + c;
    codesP[rowbase + (size_t)kt * 4096 + lane * 64 + sub + ci * 4] = cc;
  }
}

// ---------------- fused QKV projection GEMM ----------------
// C[m][n] = sum_k A[m][k] * W[n][k] + bias[n];  M=8192, N=512, K=512.
// 64x128 tile, 4 waves. A fp32 (cast fused). z=0/1: [bh][n][d]; z=2: [bh][d][n].
__global__ __launch_bounds__(256) void qkv_gemm(
    const float* __restrict__ Aq, const float* __restrict__ Ak, const float* __restrict__ Av,
    const unsigned short* __restrict__ Wqp, const unsigned short* __restrict__ Wkp,
    const unsigned short* __restrict__ Wvp,
    const float* __restrict__ bq, const float* __restrict__ bk, const float* __restrict__ bv,
    unsigned short* __restrict__ Qh, unsigned short* __restrict__ Kh,
    unsigned short* __restrict__ Vt) {
  const int z = blockIdx.z;
  const float* A = (z == 0) ? Aq : (z == 1) ? Ak : Av;
  const unsigned short* W = (z == 0) ? Wqp : (z == 1) ? Wkp : Wvp;
  const float* bias = (z == 0) ? bq : (z == 1) ? bk : bv;
  unsigned short* O = (z == 0) ? Qh : (z == 1) ? Kh : Vt;

  __shared__ __align__(16) short As[64 * 40];
  __shared__ __align__(16) short Bs[128 * 32];
  const int tid = threadIdx.x;
  const int lane = tid & 63;
  const int wave = tid >> 6;
  const int c = lane & 15;
  const int q = lane >> 4;
  const int m0 = blockIdx.x * 64;
  const int n0 = blockIdx.y * 128;
  const int wr = (wave >> 1) * 32;
  const int wc = (wave & 1) * 64;

  floatx4 acc[2][4];
#pragma unroll
  for (int i = 0; i < 2; i++)
#pragma unroll
    for (int j = 0; j < 4; j++) acc[i][j] = (floatx4)(0.0f);

  const int arow = tid >> 2, ach = tid & 3;
  const float* Ab = A + (size_t)(m0 + arow) * 512 + ach * 8;

  for (int k0 = 0; k0 < 512; k0 += 32) {
    __syncthreads();
#pragma unroll
    for (int it = 0; it < 2; it++) {
      int slot = wave * 128 + it * 64 + lane;
      int brow = slot >> 2, bch = slot & 3;
      int g = bch ^ xsw(brow);
      gload_lds16(W + (size_t)(n0 + brow) * 512 + k0 + g * 8,
                  &Bs[(size_t)(wave * 128 + it * 64) * 8]);
    }
    float4 a0 = *(const float4*)(Ab + k0);
    float4 a1 = *(const float4*)(Ab + k0 + 4);
    short8 av;
    av[0] = (short)f2bf(a0.x); av[1] = (short)f2bf(a0.y);
    av[2] = (short)f2bf(a0.z); av[3] = (short)f2bf(a0.w);
    av[4] = (short)f2bf(a1.x); av[5] = (short)f2bf(a1.y);
    av[6] = (short)f2bf(a1.z); av[7] = (short)f2bf(a1.w);
    *(short8*)(&As[arow * 40 + ach * 8]) = av;
    __syncthreads();

    short8 af[2], bfv[4];
#pragma unroll
    for (int i = 0; i < 2; i++)
      af[i] = *(const short8*)(&As[(wr + i * 16 + c) * 40 + q * 8]);
#pragma unroll
    for (int j = 0; j < 4; j++) {
      int row = wc + j * 16 + c;
      bfv[j] = *(const short8*)(&Bs[row * 32 + (q ^ xsw(row)) * 8]);
    }
#pragma unroll
    for (int i = 0; i < 2; i++)
#pragma unroll
      for (int j = 0; j < 4; j++)
        acc[i][j] = MFMA16(af[i], bfv[j], acc[i][j]);
  }

#pragma unroll
  for (int i = 0; i < 2; i++) {
    int gm0 = m0 + wr + i * 16 + q * 4;
#pragma unroll
    for (int j = 0; j < 4; j++) {
      int gn = n0 + wc + j * 16 + c;
      float bb = bias[gn];
      int h = gn >> 6, d = gn & 63;
      if (z == 2) {
        int b = gm0 >> 10, n = gm0 & 1023;
        ushort4 pk;
#pragma unroll
        for (int r = 0; r < 4; r++) pk[r] = f2bf(acc[i][j][r] + bb);
        *(ushort4*)(&Vt[(((size_t)(b * 8 + h) * 64 + d) << 10) + n]) = pk;  // [bh][d][n]
      } else {
#pragma unroll
        for (int r = 0; r < 4; r++) {
          int m = gm0 + r;
          int b = m >> 10, n = m & 1023;
          O[((((size_t)(b * 8 + h)) << 10) + n) * 64 + d] = f2bf(acc[i][j][r] + bb);
        }
      }
    }
  }
}

// ---------------- output projection GEMM (bf16 A, fp32 out) ----------------
__global__ __launch_bounds__(256) void out_gemm(const unsigned short* __restrict__ A,
                                                const unsigned short* __restrict__ W,
                                                const float* __restrict__ bias,
                                                float* __restrict__ Out) {
  __shared__ __align__(16) short As[64 * 32];
  __shared__ __align__(16) short Bs[128 * 32];
  const int tid = threadIdx.x;
  const int lane = tid & 63;
  const int wave = tid >> 6;
  const int c = lane & 15;
  const int q = lane >> 4;
  const int m0 = blockIdx.x * 64;
  const int n0 = blockIdx.y * 128;
  const int wr = (wave >> 1) * 32;
  const int wc = (wave & 1) * 64;

  floatx4 acc[2][4];
#pragma unroll
  for (int i = 0; i < 2; i++)
#pragma unroll
    for (int j = 0; j < 4; j++) acc[i][j] = (floatx4)(0.0f);

  for (int k0 = 0; k0 < 512; k0 += 32) {
    __syncthreads();
    {
      int slot = wave * 64 + lane;
      int arow = slot >> 2, ach = slot & 3;
      int g = ach ^ xsw(arow);
      gload_lds16(A + (size_t)(m0 + arow) * 512 + k0 + g * 8, &As[(size_t)(wave * 64) * 8]);
    }
#pragma unroll
    for (int it = 0; it < 2; it++) {
      int slot = wave * 128 + it * 64 + lane;
      int brow = slot >> 2, bch = slot & 3;
      int g = bch ^ xsw(brow);
      gload_lds16(W + (size_t)(n0 + brow) * 512 + k0 + g * 8,
                  &Bs[(size_t)(wave * 128 + it * 64) * 8]);
    }
    __syncthreads();

    short8 af[2], bfv[4];
#pragma unroll
    for (int i = 0; i < 2; i++) {
      int row = wr + i * 16 + c;
      af[i] = *(const short8*)(&As[row * 32 + (q ^ xsw(row)) * 8]);
    }
#pragma unroll
    for (int j = 0; j < 4; j++) {
      int row = wc + j * 16 + c;
      bfv[j] = *(const short8*)(&Bs[row * 32 + (q ^ xsw(row)) * 8]);
    }
#pragma unroll
    for (int i = 0; i < 2; i++)
#pragma unroll
      for (int j = 0; j < 4; j++)
        acc[i][j] = MFMA16(af[i], bfv[j], acc[i][j]);
  }

#pragma unroll
  for (int i = 0; i < 2; i++) {
    int gm0 = m0 + wr + i * 16 + q * 4;
#pragma unroll
    for (int j = 0; j < 4; j++) {
      int gn = n0 + wc + j * 16 + c;
      float bb = bias[gn];
#pragma unroll
      for (int r = 0; r < 4; r++)
        Out[(size_t)(gm0 + r) * 512 + gn] = acc[i][j][r] + bb;
    }
  }
}

// ---------------- barrier-free flash attention (kt-split) ----------------
// Block (gx, bh): 64 q-rows of head (b,h). Wave w: wsub=w&1 picks the 32-row
// sub-block, whalf=w>>1 picks K-tiles [whalf*4, +4). Per-wave per-kt work is
// identical to the 94 µs 32-row version (intensity preserved); occupancy is
// doubled by the kt split (1024 blocks -> 4 blocks/CU).
// NOTE: plain __launch_bounds__(256). The (256,4) variant forced a 64-VGPR
// cap -> ~92 MB scratch spills (round 5: WRITE_SIZE 100 MB, dur 110 us).
// This state fits 128 VGPR (measured, round 3) -> 4 waves/SIMD, no spills.
// No max-tracking in this softmax (plain exp), so kt-half partials merge by
// simple addition of (o, rs): waves 2,3 stash partials in (reused) P LDS,
// one barrier, waves 0,1 add + normalize + store. Main loop stays barrier-free.
__global__ __launch_bounds__(256) void attn_kernel(const unsigned short* __restrict__ Qh,
                                                   const unsigned short* __restrict__ Kh,
                                                   const unsigned short* __restrict__ Vt,
                                                   const unsigned char* __restrict__ codesP,
                                                   unsigned short* __restrict__ AO) {
  __shared__ __align__(16) unsigned short P[4][32 * 132];   // 33 KB, wave-private regions
  const int tid = threadIdx.x;
  const int lane = tid & 63;
  const int wave = tid >> 6;
  const int wsub = wave & 1;     // which 32-row sub-block
  const int whalf = wave >> 1;   // which kt half
  const int c = lane & 15;
  const int q = lane >> 4;
  const int bh = blockIdx.y;
  const int b = bh >> 3;
  const int h = bh & 7;
  const size_t base = (size_t)bh << 16;
  const int rbase = blockIdx.x * 64 + wsub * 32;
  const int rg = rbase >> 5;
  unsigned short* Pw = &P[wave][0];

  // Q A-fragments for both 16-row stripes, held all kernel
  short8 aq[2][2];
#pragma unroll
  for (int st = 0; st < 2; st++)
#pragma unroll
    for (int kk = 0; kk < 2; kk++)
      aq[st][kk] = *(const short8*)(Qh + base + (size_t)(rbase + st * 16 + c) * 64 + kk * 32 + q * 8);

  const unsigned char* cbt = codesP + (size_t)(b * 32 + rg) * 32768 + lane * 64;
  const unsigned short* Kb = Kh + base;
  const unsigned short* Vb = Vt + base;

  float rs[2][4];
#pragma unroll
  for (int st = 0; st < 2; st++)
#pragma unroll
    for (int r = 0; r < 4; r++) rs[st][r] = 0.0f;
  floatx4 o[2][4];
#pragma unroll
  for (int st = 0; st < 2; st++)
#pragma unroll
    for (int ci = 0; ci < 4; ci++) o[st][ci] = (floatx4)(0.0f);

  for (int kti = 0; kti < 4; kti++) {
    const int kt = whalf * 4 + kti;
    // ---- QK^T: S[2 stripes][8 col-tiles], K frags straight from global ----
    const unsigned short* Kt = Kb + (size_t)kt * 128 * 64;
    floatx4 s[2][8];
#pragma unroll
    for (int ci = 0; ci < 8; ci++) { s[0][ci] = (floatx4)(0.0f); s[1][ci] = (floatx4)(0.0f); }
#pragma unroll
    for (int ci = 0; ci < 8; ci++)
#pragma unroll
      for (int kk = 0; kk < 2; kk++) {
        short8 bk = *(const short8*)(Kt + (size_t)(ci * 16 + c) * 64 + kk * 32 + q * 8);
        s[0][ci] = MFMA16(aq[0][kk], bk, s[0][ci]);
        s[1][ci] = MFMA16(aq[1][kk], bk, s[1][ci]);
      }
    // ---- codes: 64 bytes/lane, pre-permuted, 4 coalesced dwordx4 ----
    const unsigned char* cp = cbt + (size_t)kt * 4096;
    uint4 w0 = *(const uint4*)(cp);
    uint4 w1 = *(const uint4*)(cp + 16);
    uint4 w2 = *(const uint4*)(cp + 32);
    uint4 w3 = *(const uint4*)(cp + 48);
    unsigned cv[16] = {w0.x, w0.y, w0.z, w0.w, w1.x, w1.y, w1.z, w1.w,
                       w2.x, w2.y, w2.z, w2.w, w3.x, w3.y, w3.z, w3.w};
    // ---- exp epilogue -> wave-private P + register row sums ----
#pragma unroll
    for (int st = 0; st < 2; st++)
#pragma unroll
      for (int ci = 0; ci < 8; ci++)
#pragma unroll
        for (int r = 0; r < 4; r++) {
          int bidx = st * 32 + ci * 4 + r;                       // compile-time
          int code = (cv[bidx >> 2] >> ((bidx & 3) * 8)) & 0xff;
          float e = (h >= code) ? exp2f(s[st][ci][r] * 0.1803368801111362f) : 0.0f;
          rs[st][r] += e;
          Pw[(st * 16 + q * 4 + r) * 132 + ci * 16 + c] = f2bf(e);
        }
    // ---- PV: wave reads back its own P (lgkmcnt ordering, no barrier) ----
#pragma unroll
    for (int ch = 0; ch < 4; ch++) {
      short8 ap0 = *(const short8*)(&Pw[(size_t)c * 132 + ch * 32 + q * 8]);
      short8 ap1 = *(const short8*)(&Pw[(size_t)(16 + c) * 132 + ch * 32 + q * 8]);
#pragma unroll
      for (int ci = 0; ci < 4; ci++) {
        short8 bv = *(const short8*)(Vb + (size_t)(ci * 16 + c) * 1024 + kt * 128 + ch * 32 + q * 8);
        o[0][ci] = MFMA16(ap0, bv, o[0][ci]);
        o[1][ci] = MFMA16(ap1, bv, o[1][ci]);
      }
    }
  }

  // ---- merge kt-half partials: waves 2,3 -> LDS, waves 0,1 accumulate ----
  // 40 floats/lane: chunks 0..7 = o[st][ci], 8..9 = rs[st][0..3].
  // float4 slot fidx = (wsub*10 + chunk)*64 + lane  (20.5 KB, reuses P).
  float* Pf = (float*)&P[0][0];
  __syncthreads();
  if (whalf == 1) {
#pragma unroll
    for (int st = 0; st < 2; st++)
#pragma unroll
      for (int ci = 0; ci < 4; ci++)
        *(floatx4*)&Pf[(((wsub * 10 + st * 4 + ci) * 64) + lane) * 4] = o[st][ci];
#pragma unroll
    for (int st = 0; st < 2; st++) {
      floatx4 rr;
#pragma unroll
      for (int r = 0; r < 4; r++) rr[r] = rs[st][r];
      *(floatx4*)&Pf[(((wsub * 10 + 8 + st) * 64) + lane) * 4] = rr;
    }
  }
  __syncthreads();
  if (whalf == 1) return;

#pragma unroll
  for (int st = 0; st < 2; st++)
#pragma unroll
    for (int ci = 0; ci < 4; ci++) {
      floatx4 p = *(const floatx4*)&Pf[(((wsub * 10 + st * 4 + ci) * 64) + lane) * 4];
      o[st][ci] += p;
    }
#pragma unroll
  for (int st = 0; st < 2; st++) {
    floatx4 pr = *(const floatx4*)&Pf[(((wsub * 10 + 8 + st) * 64) + lane) * 4];
#pragma unroll
    for (int r = 0; r < 4; r++) rs[st][r] += pr[r];
  }

  // ---- normalize + write (wave-local) ----
  float inv[2][4];
#pragma unroll
  for (int st = 0; st < 2; st++)
#pragma unroll
    for (int r = 0; r < 4; r++) {
      float v = rs[st][r];
      v += __shfl_xor(v, 1); v += __shfl_xor(v, 2);
      v += __shfl_xor(v, 4); v += __shfl_xor(v, 8);
      inv[st][r] = 1.0f / v;
    }
#pragma unroll
  for (int st = 0; st < 2; st++)
#pragma unroll
    for (int r = 0; r < 4; r++) {
      int n = rbase + st * 16 + q * 4 + r;
      size_t ob = ((size_t)((b << 10) + n)) * 512 + h * 64;
#pragma unroll
      for (int ci = 0; ci < 4; ci++)
        AO[ob + ci * 16 + c] = f2bf(o[st][ci][r] * inv[st][r]);
    }
}

// ---------------- launcher ----------------
extern "C" void kernel_launch(void* const* d_in, const int* in_sizes, int n_in,
                              void* d_out, int out_size, void* d_ws, size_t ws_size,
                              hipStream_t stream) {
  const float* query = (const float*)d_in[0];
  const float* key_  = (const float*)d_in[1];
  const float* value = (const float*)d_in[2];
  const float* dist  = (const float*)d_in[3];
  const int*   mask  = (const int*)d_in[4];
  const float* Wq = (const float*)d_in[5];
  const float* bq = (const float*)d_in[6];
  const float* Wk = (const float*)d_in[7];
  const float* bk = (const float*)d_in[8];
  const float* Wv = (const float*)d_in[9];
  const float* bv = (const float*)d_in[10];
  const float* Wo = (const float*)d_in[11];
  const float* bo = (const float*)d_in[12];

  char* ws = (char*)d_ws;
  size_t off = 0;
  auto alloc = [&](size_t bytes) -> char* {
    char* p = ws + off;
    off += (bytes + 255) & ~(size_t)255;
    return p;
  };
  const size_t NQKV = 8192ull * 512;
  unsigned short* wq16 = (unsigned short*)alloc(512ull * 512 * 2);
  unsigned short* wk16 = (unsigned short*)alloc(512ull * 512 * 2);
  unsigned short* wv16 = (unsigned short*)alloc(512ull * 512 * 2);
  unsigned short* wo16 = (unsigned short*)alloc(512ull * 512 * 2);
  unsigned short* Qh = (unsigned short*)alloc(NQKV * 2);
  unsigned short* Kh = (unsigned short*)alloc(NQKV * 2);
  unsigned short* Vt = (unsigned short*)alloc(NQKV * 2);
  unsigned short* AO = (unsigned short*)alloc(NQKV * 2);
  unsigned char*  codesP = (unsigned char*)alloc(8ull * 1024 * 1024);

  wcast_kernel<<<1024, 256, 0, stream>>>(Wq, Wk, Wv, Wo, wq16, wk16, wv16, wo16);
  codes_kernel<<<8192, 256, 0, stream>>>(dist, mask, codesP);
  qkv_gemm<<<dim3(128, 4, 3), 256, 0, stream>>>(query, key_, value, wq16, wk16, wv16,
                                                bq, bk, bv, Qh, Kh, Vt);
  attn_kernel<<<dim3(16, 64), 256, 0, stream>>>(Qh, Kh, Vt, codesP, AO);
  out_gemm<<<dim3(128, 4), 256, 0, stream>>>(AO, wo16, bo, (float*)d_out);
}

// Round 4
// 290.505 us; speedup vs baseline: 1.0614x; 1.0614x over previous
//
#include <hip/hip_runtime.h>
#include <stdint.h>

// ---------------------------------------------------------------------------
// MultiHeadedAttention: B=8, N=1024, E=512, H=8, D_K=64
// bf16 MFMA pipeline. Round 7: register-ceiling fix. Diagnosis: occupancy was
// stuck at 2 waves/SIMD because TOTAL unified regs (arch VGPR + MFMA acc)
// was ~220/thread (s[2][8]=64 acc live across QK^T->exp was the biggest
// block). Fix: process the 128-col K tile in four 32-col quarters so s
// shrinks to s[2][2]=16 regs with short liveness; __launch_bounds__(256,3)
// guarantees >=3 waves/SIMD; sched_barrier(0) at quarter boundaries stops
// the scheduler re-inflating liveness by hoisting K loads. kt-split retained
// (1024 blocks) so the grid can supply 3-4 blocks/CU.
// ---------------------------------------------------------------------------

typedef __attribute__((ext_vector_type(8))) short short8;
typedef __attribute__((ext_vector_type(4))) float floatx4;

#define MFMA16(a, b, c) __builtin_amdgcn_mfma_f32_16x16x32_bf16((a), (b), (c), 0, 0, 0)

static __device__ __forceinline__ unsigned short f2bf(float f) {
  union { float f; unsigned u; } v; v.f = f;
  unsigned r = v.u + 0x7fffu + ((v.u >> 16) & 1u);   // RNE
  return (unsigned short)(r >> 16);
}

// async global->LDS 16B/lane. LDS dest is wave-uniform base + lane*16 (m104).
static __device__ __forceinline__ void gload_lds16(const void* g, void* l) {
  __builtin_amdgcn_global_load_lds((const __attribute__((address_space(1))) unsigned int*)g,
                                   (__attribute__((address_space(3))) unsigned int*)l,
                                   16, 0, 0);
}
// chunk swizzle for unpadded 32-elem-wide bf16 LDS tiles (GEMM staging).
static __device__ __forceinline__ int xsw(int row) { return (row & 3) ^ ((row >> 2) & 3); }

// ---------------- weight cast fp32 -> bf16 (all 4 at once) ----------------
__global__ void wcast_kernel(const float* __restrict__ Wq, const float* __restrict__ Wk,
                             const float* __restrict__ Wv, const float* __restrict__ Wo,
                             unsigned short* __restrict__ o0, unsigned short* __restrict__ o1,
                             unsigned short* __restrict__ o2, unsigned short* __restrict__ o3) {
  int i = blockIdx.x * blockDim.x + threadIdx.x;   // 0..262143
  int w = i >> 16, loc = i & 65535;
  const float* s = (w == 0) ? Wq : (w == 1) ? Wk : (w == 2) ? Wv : Wo;
  unsigned short* d = (w == 0) ? o0 : (w == 1) ? o1 : (w == 2) ? o2 : o3;
  float4 v = ((const float4*)s)[loc];
  ushort4 o;
  o.x = f2bf(v.x); o.y = f2bf(v.y); o.z = f2bf(v.z); o.w = f2bf(v.w);
  ((ushort4*)d)[loc] = o;
}

// ---------------- dist+mask -> permuted code bytes ----------------
// allowed(h) <=> h >= code (DIST_BAR ascending). 0 on row/col 0; 9 if mask==0.
// Output layout matches the attn exp-epilogue exactly:
//   codesP[ (((b*32+rg)*8 + kt)*64 + lane)*64 + st*32 + ci*4 + r ]
// where row = rg*32 + st*16 + q*4 + r, col = kt*128 + ci*16 + c, lane = q*16+c.
// The attn kernel reads 8-byte chunks per (st, quarter): cp[st*32 + j*8 .. +7].
__global__ void codes_kernel(const float* __restrict__ dist, const int* __restrict__ mask,
                             unsigned char* __restrict__ codesP) {
  int t = blockIdx.x * blockDim.x + threadIdx.x;   // over B*N*N/4
  int flat = t << 2;
  int b = flat >> 20;
  int rem = flat & ((1 << 20) - 1);
  int row = rem >> 10;
  int col0 = rem & 1023;
  float4 d4 = ((const float4*)dist)[t];
  int4 m4 = ((const int4*)mask)[t];
  float dv[4] = {d4.x, d4.y, d4.z, d4.w};
  int mv[4] = {m4.x, m4.y, m4.z, m4.w};
  int rg = row >> 5;
  int st = (row >> 4) & 1;
  int qq = (row >> 2) & 3;
  int r = row & 3;
  size_t rowbase = (size_t)(b * 32 + rg) * 32768;   // *8 kt *4096
  int sub = st * 32 + r;
#pragma unroll
  for (int u = 0; u < 4; u++) {
    int col = col0 + u;
    float d = dv[u];
    int hmin = (d >= 0.2f) + (d >= 0.3f) + (d >= 0.4f) + (d >= 0.5f) +
               (d >= 0.6f) + (d >= 0.7f) + (d >= 0.8f) + (d >= 0.9f);
    unsigned char cc = (unsigned char)hmin;
    if (row == 0 || col == 0) cc = 0;
    if (mv[u] == 0) cc = 9;
    int kt = col >> 7, ci = (col >> 4) & 7, c = col & 15;
    int lane = qq * 16 + c;
    codesP[rowbase + (size_t)kt * 4096 + lane * 64 + sub + ci * 4] = cc;
  }
}

// ---------------- fused QKV projection GEMM ----------------
// C[m][n] = sum_k A[m][k] * W[n][k] + bias[n];  M=8192, N=512, K=512.
// 64x128 tile, 4 waves. A fp32 (cast fused). z=0/1: [bh][n][d]; z=2: [bh][d][n].
__global__ __launch_bounds__(256) void qkv_gemm(
    const float* __restrict__ Aq, const float* __restrict__ Ak, const float* __restrict__ Av,
    const unsigned short* __restrict__ Wqp, const unsigned short* __restrict__ Wkp,
    const unsigned short* __restrict__ Wvp,
    const float* __restrict__ bq, const float* __restrict__ bk, const float* __restrict__ bv,
    unsigned short* __restrict__ Qh, unsigned short* __restrict__ Kh,
    unsigned short* __restrict__ Vt) {
  const int z = blockIdx.z;
  const float* A = (z == 0) ? Aq : (z == 1) ? Ak : Av;
  const unsigned short* W = (z == 0) ? Wqp : (z == 1) ? Wkp : Wvp;
  const float* bias = (z == 0) ? bq : (z == 1) ? bk : bv;
  unsigned short* O = (z == 0) ? Qh : (z == 1) ? Kh : Vt;

  __shared__ __align__(16) short As[64 * 40];
  __shared__ __align__(16) short Bs[128 * 32];
  const int tid = threadIdx.x;
  const int lane = tid & 63;
  const int wave = tid >> 6;
  const int c = lane & 15;
  const int q = lane >> 4;
  const int m0 = blockIdx.x * 64;
  const int n0 = blockIdx.y * 128;
  const int wr = (wave >> 1) * 32;
  const int wc = (wave & 1) * 64;

  floatx4 acc[2][4];
#pragma unroll
  for (int i = 0; i < 2; i++)
#pragma unroll
    for (int j = 0; j < 4; j++) acc[i][j] = (floatx4)(0.0f);

  const int arow = tid >> 2, ach = tid & 3;
  const float* Ab = A + (size_t)(m0 + arow) * 512 + ach * 8;

  for (int k0 = 0; k0 < 512; k0 += 32) {
    __syncthreads();
#pragma unroll
    for (int it = 0; it < 2; it++) {
      int slot = wave * 128 + it * 64 + lane;
      int brow = slot >> 2, bch = slot & 3;
      int g = bch ^ xsw(brow);
      gload_lds16(W + (size_t)(n0 + brow) * 512 + k0 + g * 8,
                  &Bs[(size_t)(wave * 128 + it * 64) * 8]);
    }
    float4 a0 = *(const float4*)(Ab + k0);
    float4 a1 = *(const float4*)(Ab + k0 + 4);
    short8 av;
    av[0] = (short)f2bf(a0.x); av[1] = (short)f2bf(a0.y);
    av[2] = (short)f2bf(a0.z); av[3] = (short)f2bf(a0.w);
    av[4] = (short)f2bf(a1.x); av[5] = (short)f2bf(a1.y);
    av[6] = (short)f2bf(a1.z); av[7] = (short)f2bf(a1.w);
    *(short8*)(&As[arow * 40 + ach * 8]) = av;
    __syncthreads();

    short8 af[2], bfv[4];
#pragma unroll
    for (int i = 0; i < 2; i++)
      af[i] = *(const short8*)(&As[(wr + i * 16 + c) * 40 + q * 8]);
#pragma unroll
    for (int j = 0; j < 4; j++) {
      int row = wc + j * 16 + c;
      bfv[j] = *(const short8*)(&Bs[row * 32 + (q ^ xsw(row)) * 8]);
    }
#pragma unroll
    for (int i = 0; i < 2; i++)
#pragma unroll
      for (int j = 0; j < 4; j++)
        acc[i][j] = MFMA16(af[i], bfv[j], acc[i][j]);
  }

#pragma unroll
  for (int i = 0; i < 2; i++) {
    int gm0 = m0 + wr + i * 16 + q * 4;
#pragma unroll
    for (int j = 0; j < 4; j++) {
      int gn = n0 + wc + j * 16 + c;
      float bb = bias[gn];
      int h = gn >> 6, d = gn & 63;
      if (z == 2) {
        int b = gm0 >> 10, n = gm0 & 1023;
        ushort4 pk;
#pragma unroll
        for (int r = 0; r < 4; r++) pk[r] = f2bf(acc[i][j][r] + bb);
        *(ushort4*)(&Vt[(((size_t)(b * 8 + h) * 64 + d) << 10) + n]) = pk;  // [bh][d][n]
      } else {
#pragma unroll
        for (int r = 0; r < 4; r++) {
          int m = gm0 + r;
          int b = m >> 10, n = m & 1023;
          O[((((size_t)(b * 8 + h)) << 10) + n) * 64 + d] = f2bf(acc[i][j][r] + bb);
        }
      }
    }
  }
}

// ---------------- output projection GEMM (bf16 A, fp32 out) ----------------
__global__ __launch_bounds__(256) void out_gemm(const unsigned short* __restrict__ A,
                                                const unsigned short* __restrict__ W,
                                                const float* __restrict__ bias,
                                                float* __restrict__ Out) {
  __shared__ __align__(16) short As[64 * 32];
  __shared__ __align__(16) short Bs[128 * 32];
  const int tid = threadIdx.x;
  const int lane = tid & 63;
  const int wave = tid >> 6;
  const int c = lane & 15;
  const int q = lane >> 4;
  const int m0 = blockIdx.x * 64;
  const int n0 = blockIdx.y * 128;
  const int wr = (wave >> 1) * 32;
  const int wc = (wave & 1) * 64;

  floatx4 acc[2][4];
#pragma unroll
  for (int i = 0; i < 2; i++)
#pragma unroll
    for (int j = 0; j < 4; j++) acc[i][j] = (floatx4)(0.0f);

  for (int k0 = 0; k0 < 512; k0 += 32) {
    __syncthreads();
    {
      int slot = wave * 64 + lane;
      int arow = slot >> 2, ach = slot & 3;
      int g = ach ^ xsw(arow);
      gload_lds16(A + (size_t)(m0 + arow) * 512 + k0 + g * 8, &As[(size_t)(wave * 64) * 8]);
    }
#pragma unroll
    for (int it = 0; it < 2; it++) {
      int slot = wave * 128 + it * 64 + lane;
      int brow = slot >> 2, bch = slot & 3;
      int g = bch ^ xsw(brow);
      gload_lds16(W + (size_t)(n0 + brow) * 512 + k0 + g * 8,
                  &Bs[(size_t)(wave * 128 + it * 64) * 8]);
    }
    __syncthreads();

    short8 af[2], bfv[4];
#pragma unroll
    for (int i = 0; i < 2; i++) {
      int row = wr + i * 16 + c;
      af[i] = *(const short8*)(&As[row * 32 + (q ^ xsw(row)) * 8]);
    }
#pragma unroll
    for (int j = 0; j < 4; j++) {
      int row = wc + j * 16 + c;
      bfv[j] = *(const short8*)(&Bs[row * 32 + (q ^ xsw(row)) * 8]);
    }
#pragma unroll
    for (int i = 0; i < 2; i++)
#pragma unroll
      for (int j = 0; j < 4; j++)
        acc[i][j] = MFMA16(af[i], bfv[j], acc[i][j]);
  }

#pragma unroll
  for (int i = 0; i < 2; i++) {
    int gm0 = m0 + wr + i * 16 + q * 4;
#pragma unroll
    for (int j = 0; j < 4; j++) {
      int gn = n0 + wc + j * 16 + c;
      float bb = bias[gn];
#pragma unroll
      for (int r = 0; r < 4; r++)
        Out[(size_t)(gm0 + r) * 512 + gn] = acc[i][j][r] + bb;
    }
  }
}

// ---------------- barrier-free flash attention (kt-split, quarter-tiled) ----
// Block (gx, bh): 64 q-rows of head (b,h). Wave w: wsub=w&1 picks the 32-row
// sub-block, whalf=w>>1 picks K-tiles [whalf*4, +4).
// Register discipline: the 128-col K tile is processed in four 32-col
// quarters; score acc is s[2][2] (16 regs, short liveness) instead of the
// old s[2][8] (64 regs live across the whole tile) that pushed total unified
// regs to ~220 and capped residency at 2 waves/SIMD (rounds 3-6).
// sched_barrier(0) between quarters keeps the scheduler from hoisting all
// K loads and re-inflating liveness. launch_bounds (256,3) => <=170-reg
// budget, >=3 waves/SIMD guaranteed; true liveness ~130 so no spill storm.
// kt-half partials merge by addition via one LDS round-trip (2 barriers).
__global__ __launch_bounds__(256, 3) void attn_kernel(const unsigned short* __restrict__ Qh,
                                                      const unsigned short* __restrict__ Kh,
                                                      const unsigned short* __restrict__ Vt,
                                                      const unsigned char* __restrict__ codesP,
                                                      unsigned short* __restrict__ AO) {
  __shared__ __align__(16) unsigned short P[4][32 * 132];   // 33 KB, wave-private regions
  const int tid = threadIdx.x;
  const int lane = tid & 63;
  const int wave = tid >> 6;
  const int wsub = wave & 1;     // which 32-row sub-block
  const int whalf = wave >> 1;   // which kt half
  const int c = lane & 15;
  const int q = lane >> 4;
  const int bh = blockIdx.y;
  const int b = bh >> 3;
  const int h = bh & 7;
  const size_t base = (size_t)bh << 16;
  const int rbase = blockIdx.x * 64 + wsub * 32;
  const int rg = rbase >> 5;
  unsigned short* Pw = &P[wave][0];

  // Q A-fragments for both 16-row stripes, held all kernel
  short8 aq[2][2];
#pragma unroll
  for (int st = 0; st < 2; st++)
#pragma unroll
    for (int kk = 0; kk < 2; kk++)
      aq[st][kk] = *(const short8*)(Qh + base + (size_t)(rbase + st * 16 + c) * 64 + kk * 32 + q * 8);

  const unsigned char* cbt = codesP + (size_t)(b * 32 + rg) * 32768 + lane * 64;
  const unsigned short* Kb = Kh + base;
  const unsigned short* Vb = Vt + base;

  float rs[2][4];
#pragma unroll
  for (int st = 0; st < 2; st++)
#pragma unroll
    for (int r = 0; r < 4; r++) rs[st][r] = 0.0f;
  floatx4 o[2][4];
#pragma unroll
  for (int st = 0; st < 2; st++)
#pragma unroll
    for (int ci = 0; ci < 4; ci++) o[st][ci] = (floatx4)(0.0f);

  for (int kti = 0; kti < 4; kti++) {
    const int kt = whalf * 4 + kti;
    const unsigned short* Kt = Kb + (size_t)kt * 128 * 64;
    const unsigned char* cp = cbt + (size_t)kt * 4096;
#pragma unroll
    for (int j = 0; j < 4; j++) {
      // ---- QK^T quarter: ci = 2j, 2j+1 ----
      floatx4 s[2][2];
      s[0][0] = (floatx4)(0.0f); s[0][1] = (floatx4)(0.0f);
      s[1][0] = (floatx4)(0.0f); s[1][1] = (floatx4)(0.0f);
#pragma unroll
      for (int u = 0; u < 2; u++) {
        int ci = 2 * j + u;
#pragma unroll
        for (int kk = 0; kk < 2; kk++) {
          short8 bk = *(const short8*)(Kt + (size_t)(ci * 16 + c) * 64 + kk * 32 + q * 8);
          s[0][u] = MFMA16(aq[0][kk], bk, s[0][u]);
          s[1][u] = MFMA16(aq[1][kk], bk, s[1][u]);
        }
      }
      // ---- codes for this quarter: 8 bytes per stripe ----
      uint2 cw0 = *(const uint2*)(cp + j * 8);        // st=0: (u,r) bytes
      uint2 cw1 = *(const uint2*)(cp + 32 + j * 8);   // st=1
      // ---- exp -> wave-private P + register row sums ----
#pragma unroll
      for (int st = 0; st < 2; st++) {
        unsigned we = st ? cw1.x : cw0.x;
        unsigned wo = st ? cw1.y : cw0.y;
#pragma unroll
        for (int u = 0; u < 2; u++) {
          unsigned wv = u ? wo : we;
          int ci = 2 * j + u;
#pragma unroll
          for (int r = 0; r < 4; r++) {
            int code = (wv >> (r * 8)) & 0xff;
            float e = (h >= code) ? exp2f(s[st][u][r] * 0.1803368801111362f) : 0.0f;
            rs[st][r] += e;
            Pw[(st * 16 + q * 4 + r) * 132 + ci * 16 + c] = f2bf(e);
          }
        }
      }
      // ---- PV quarter: P k-cols [j*32, +32) x V rows [kt*128+j*32, +32) ----
      short8 ap0 = *(const short8*)(&Pw[(size_t)c * 132 + j * 32 + q * 8]);
      short8 ap1 = *(const short8*)(&Pw[(size_t)(16 + c) * 132 + j * 32 + q * 8]);
#pragma unroll
      for (int co = 0; co < 4; co++) {
        short8 bv = *(const short8*)(Vb + (size_t)(co * 16 + c) * 1024 + kt * 128 + j * 32 + q * 8);
        o[0][co] = MFMA16(ap0, bv, o[0][co]);
        o[1][co] = MFMA16(ap1, bv, o[1][co]);
      }
      __builtin_amdgcn_sched_barrier(0);   // cap liveness at quarter boundary
    }
  }

  // ---- merge kt-half partials: waves 2,3 -> LDS, waves 0,1 accumulate ----
  // 40 floats/lane: chunks 0..7 = o[st][ci], 8..9 = rs[st][0..3].
  // float4 slot fidx = (wsub*10 + chunk)*64 + lane  (20.5 KB, reuses P).
  float* Pf = (float*)&P[0][0];
  __syncthreads();
  if (whalf == 1) {
#pragma unroll
    for (int st = 0; st < 2; st++)
#pragma unroll
      for (int ci = 0; ci < 4; ci++)
        *(floatx4*)&Pf[(((wsub * 10 + st * 4 + ci) * 64) + lane) * 4] = o[st][ci];
#pragma unroll
    for (int st = 0; st < 2; st++) {
      floatx4 rr;
#pragma unroll
      for (int r = 0; r < 4; r++) rr[r] = rs[st][r];
      *(floatx4*)&Pf[(((wsub * 10 + 8 + st) * 64) + lane) * 4] = rr;
    }
  }
  __syncthreads();
  if (whalf == 1) return;

#pragma unroll
  for (int st = 0; st < 2; st++)
#pragma unroll
    for (int ci = 0; ci < 4; ci++) {
      floatx4 p = *(const floatx4*)&Pf[(((wsub * 10 + st * 4 + ci) * 64) + lane) * 4];
      o[st][ci] += p;
    }
#pragma unroll
  for (int st = 0; st < 2; st++) {
    floatx4 pr = *(const floatx4*)&Pf[(((wsub * 10 + 8 + st) * 64) + lane) * 4];
#pragma unroll
    for (int r = 0; r < 4; r++) rs[st][r] += pr[r];
  }

  // ---- normalize + write (wave-local) ----
  float inv[2][4];
#pragma unroll
  for (int st = 0; st < 2; st++)
#pragma unroll
    for (int r = 0; r < 4; r++) {
      float v = rs[st][r];
      v += __shfl_xor(v, 1); v += __shfl_xor(v, 2);
      v += __shfl_xor(v, 4); v += __shfl_xor(v, 8);
      inv[st][r] = 1.0f / v;
    }
#pragma unroll
  for (int st = 0; st < 2; st++)
#pragma unroll
    for (int r = 0; r < 4; r++) {
      int n = rbase + st * 16 + q * 4 + r;
      size_t ob = ((size_t)((b << 10) + n)) * 512 + h * 64;
#pragma unroll
      for (int ci = 0; ci < 4; ci++)
        AO[ob + ci * 16 + c] = f2bf(o[st][ci][r] * inv[st][r]);
    }
}

// ---------------- launcher ----------------
extern "C" void kernel_launch(void* const* d_in, const int* in_sizes, int n_in,
                              void* d_out, int out_size, void* d_ws, size_t ws_size,
                              hipStream_t stream) {
  const float* query = (const float*)d_in[0];
  const float* key_  = (const float*)d_in[1];
  const float* value = (const float*)d_in[2];
  const float* dist  = (const float*)d_in[3];
  const int*   mask  = (const int*)d_in[4];
  const float* Wq = (const float*)d_in[5];
  const float* bq = (const float*)d_in[6];
  const float* Wk = (const float*)d_in[7];
  const float* bk = (const float*)d_in[8];
  const float* Wv = (const float*)d_in[9];
  const float* bv = (const float*)d_in[10];
  const float* Wo = (const float*)d_in[11];
  const float* bo = (const float*)d_in[12];

  char* ws = (char*)d_ws;
  size_t off = 0;
  auto alloc = [&](size_t bytes) -> char* {
    char* p = ws + off;
    off += (bytes + 255) & ~(size_t)255;
    return p;
  };
  const size_t NQKV = 8192ull * 512;
  unsigned short* wq16 = (unsigned short*)alloc(512ull * 512 * 2);
  unsigned short* wk16 = (unsigned short*)alloc(512ull * 512 * 2);
  unsigned short* wv16 = (unsigned short*)alloc(512ull * 512 * 2);
  unsigned short* wo16 = (unsigned short*)alloc(512ull * 512 * 2);
  unsigned short* Qh = (unsigned short*)alloc(NQKV * 2);
  unsigned short* Kh = (unsigned short*)alloc(NQKV * 2);
  unsigned short* Vt = (unsigned short*)alloc(NQKV * 2);
  unsigned short* AO = (unsigned short*)alloc(NQKV * 2);
  unsigned char*  codesP = (unsigned char*)alloc(8ull * 1024 * 1024);

  wcast_kernel<<<1024, 256, 0, stream>>>(Wq, Wk, Wv, Wo, wq16, wk16, wv16, wo16);
  codes_kernel<<<8192, 256, 0, stream>>>(dist, mask, codesP);
  qkv_gemm<<<dim3(128, 4, 3), 256, 0, stream>>>(query, key_, value, wq16, wk16, wv16,
                                                bq, bk, bv, Qh, Kh, Vt);
  attn_kernel<<<dim3(16, 64), 256, 0, stream>>>(Qh, Kh, Vt, codesP, AO);
  out_gemm<<<dim3(128, 4), 256, 0, stream>>>(AO, wo16, bo, (float*)d_out);
}

// Round 5
// 283.031 us; speedup vs baseline: 1.0894x; 1.0264x over previous
//
#include <hip/hip_runtime.h>
#include <stdint.h>

// ---------------------------------------------------------------------------
// MultiHeadedAttention: B=8, N=1024, E=512, H=8, D_K=64
// bf16 MFMA pipeline. Round 8: swapped-QK^T epilogue. QK^T computed as
// mfma(K,Q) so each lane holds 4 k-consecutive P values per (st,ci):
// pack with v_cvt_pk_bf16_f32 (2 instr) and store one ds_write_b64 — the
// P tile lands in the same row-major layout the proven PV b128 read uses.
// Per kt: 64 b16 writes -> 16 b64 writes; ~256 f2bf VALU -> 32 cvt_pk;
// row sums become 1 scalar/stripe/lane. kt-split + quarter tiling retained.
// ---------------------------------------------------------------------------

typedef __attribute__((ext_vector_type(8))) short short8;
typedef __attribute__((ext_vector_type(4))) float floatx4;

#define MFMA16(a, b, c) __builtin_amdgcn_mfma_f32_16x16x32_bf16((a), (b), (c), 0, 0, 0)

static __device__ __forceinline__ unsigned short f2bf(float f) {
  union { float f; unsigned u; } v; v.f = f;
  unsigned r = v.u + 0x7fffu + ((v.u >> 16) & 1u);   // RNE
  return (unsigned short)(r >> 16);
}

// async global->LDS 16B/lane. LDS dest is wave-uniform base + lane*16 (m104).
static __device__ __forceinline__ void gload_lds16(const void* g, void* l) {
  __builtin_amdgcn_global_load_lds((const __attribute__((address_space(1))) unsigned int*)g,
                                   (__attribute__((address_space(3))) unsigned int*)l,
                                   16, 0, 0);
}
// chunk swizzle for unpadded 32-elem-wide bf16 LDS tiles (GEMM staging).
static __device__ __forceinline__ int xsw(int row) { return (row & 3) ^ ((row >> 2) & 3); }

// ---------------- weight cast fp32 -> bf16 (all 4 at once) ----------------
__global__ void wcast_kernel(const float* __restrict__ Wq, const float* __restrict__ Wk,
                             const float* __restrict__ Wv, const float* __restrict__ Wo,
                             unsigned short* __restrict__ o0, unsigned short* __restrict__ o1,
                             unsigned short* __restrict__ o2, unsigned short* __restrict__ o3) {
  int i = blockIdx.x * blockDim.x + threadIdx.x;   // 0..262143
  int w = i >> 16, loc = i & 65535;
  const float* s = (w == 0) ? Wq : (w == 1) ? Wk : (w == 2) ? Wv : Wo;
  unsigned short* d = (w == 0) ? o0 : (w == 1) ? o1 : (w == 2) ? o2 : o3;
  float4 v = ((const float4*)s)[loc];
  ushort4 o;
  o.x = f2bf(v.x); o.y = f2bf(v.y); o.z = f2bf(v.z); o.w = f2bf(v.w);
  ((ushort4*)d)[loc] = o;
}

// ---------------- dist+mask -> permuted code bytes ----------------
// allowed(h) <=> h >= code (DIST_BAR ascending). 0 on row/col 0; 9 if mask==0.
// Layout matches the SWAPPED-QK^T attn epilogue: element
//   (q-row = rg*32 + st*16 + c, k-col = kt*128 + ci*16 + hi*4 + r)
// is held by attn lane = hi*16 + c and read at byte st*32 + ci*4 + r of that
// lane's 64-byte block:
//   codesP[ (((b*32+rg)*8 + kt)*64 + lane)*64 + st*32 + ci*4 + r ]
// Each thread here covers 4 consecutive cols (same ci,hi; r=0..3) -> one
// packed u32 store.
__global__ void codes_kernel(const float* __restrict__ dist, const int* __restrict__ mask,
                             unsigned char* __restrict__ codesP) {
  int t = blockIdx.x * blockDim.x + threadIdx.x;   // over B*N*N/4
  int flat = t << 2;
  int b = flat >> 20;
  int rem = flat & ((1 << 20) - 1);
  int row = rem >> 10;
  int col0 = rem & 1023;                            // multiple of 4
  float4 d4 = ((const float4*)dist)[t];
  int4 m4 = ((const int4*)mask)[t];
  float dv[4] = {d4.x, d4.y, d4.z, d4.w};
  int mv[4] = {m4.x, m4.y, m4.z, m4.w};
  int rg = row >> 5;
  int st = (row >> 4) & 1;
  int c = row & 15;
  size_t rowbase = (size_t)(b * 32 + rg) * 32768;   // *8 kt *4096
  int kt = col0 >> 7;
  int colk = col0 & 127;
  int ci = colk >> 4;
  int hi = (colk >> 2) & 3;
  int lane = hi * 16 + c;
  unsigned pack = 0;
#pragma unroll
  for (int u = 0; u < 4; u++) {
    int col = col0 + u;
    float d = dv[u];
    int hmin = (d >= 0.2f) + (d >= 0.3f) + (d >= 0.4f) + (d >= 0.5f) +
               (d >= 0.6f) + (d >= 0.7f) + (d >= 0.8f) + (d >= 0.9f);
    unsigned cc = (unsigned)hmin;
    if (row == 0 || col == 0) cc = 0;
    if (mv[u] == 0) cc = 9;
    pack |= cc << (u * 8);
  }
  *(unsigned*)&codesP[rowbase + (size_t)kt * 4096 + lane * 64 + st * 32 + ci * 4] = pack;
}

// ---------------- fused QKV projection GEMM ----------------
// C[m][n] = sum_k A[m][k] * W[n][k] + bias[n];  M=8192, N=512, K=512.
// 64x128 tile, 4 waves. A fp32 (cast fused). z=0/1: [bh][n][d]; z=2: [bh][d][n].
__global__ __launch_bounds__(256) void qkv_gemm(
    const float* __restrict__ Aq, const float* __restrict__ Ak, const float* __restrict__ Av,
    const unsigned short* __restrict__ Wqp, const unsigned short* __restrict__ Wkp,
    const unsigned short* __restrict__ Wvp,
    const float* __restrict__ bq, const float* __restrict__ bk, const float* __restrict__ bv,
    unsigned short* __restrict__ Qh, unsigned short* __restrict__ Kh,
    unsigned short* __restrict__ Vt) {
  const int z = blockIdx.z;
  const float* A = (z == 0) ? Aq : (z == 1) ? Ak : Av;
  const unsigned short* W = (z == 0) ? Wqp : (z == 1) ? Wkp : Wvp;
  const float* bias = (z == 0) ? bq : (z == 1) ? bk : bv;
  unsigned short* O = (z == 0) ? Qh : (z == 1) ? Kh : Vt;

  __shared__ __align__(16) short As[64 * 40];
  __shared__ __align__(16) short Bs[128 * 32];
  const int tid = threadIdx.x;
  const int lane = tid & 63;
  const int wave = tid >> 6;
  const int c = lane & 15;
  const int q = lane >> 4;
  const int m0 = blockIdx.x * 64;
  const int n0 = blockIdx.y * 128;
  const int wr = (wave >> 1) * 32;
  const int wc = (wave & 1) * 64;

  floatx4 acc[2][4];
#pragma unroll
  for (int i = 0; i < 2; i++)
#pragma unroll
    for (int j = 0; j < 4; j++) acc[i][j] = (floatx4)(0.0f);

  const int arow = tid >> 2, ach = tid & 3;
  const float* Ab = A + (size_t)(m0 + arow) * 512 + ach * 8;

  for (int k0 = 0; k0 < 512; k0 += 32) {
    __syncthreads();
#pragma unroll
    for (int it = 0; it < 2; it++) {
      int slot = wave * 128 + it * 64 + lane;
      int brow = slot >> 2, bch = slot & 3;
      int g = bch ^ xsw(brow);
      gload_lds16(W + (size_t)(n0 + brow) * 512 + k0 + g * 8,
                  &Bs[(size_t)(wave * 128 + it * 64) * 8]);
    }
    float4 a0 = *(const float4*)(Ab + k0);
    float4 a1 = *(const float4*)(Ab + k0 + 4);
    short8 av;
    av[0] = (short)f2bf(a0.x); av[1] = (short)f2bf(a0.y);
    av[2] = (short)f2bf(a0.z); av[3] = (short)f2bf(a0.w);
    av[4] = (short)f2bf(a1.x); av[5] = (short)f2bf(a1.y);
    av[6] = (short)f2bf(a1.z); av[7] = (short)f2bf(a1.w);
    *(short8*)(&As[arow * 40 + ach * 8]) = av;
    __syncthreads();

    short8 af[2], bfv[4];
#pragma unroll
    for (int i = 0; i < 2; i++)
      af[i] = *(const short8*)(&As[(wr + i * 16 + c) * 40 + q * 8]);
#pragma unroll
    for (int j = 0; j < 4; j++) {
      int row = wc + j * 16 + c;
      bfv[j] = *(const short8*)(&Bs[row * 32 + (q ^ xsw(row)) * 8]);
    }
#pragma unroll
    for (int i = 0; i < 2; i++)
#pragma unroll
      for (int j = 0; j < 4; j++)
        acc[i][j] = MFMA16(af[i], bfv[j], acc[i][j]);
  }

#pragma unroll
  for (int i = 0; i < 2; i++) {
    int gm0 = m0 + wr + i * 16 + q * 4;
#pragma unroll
    for (int j = 0; j < 4; j++) {
      int gn = n0 + wc + j * 16 + c;
      float bb = bias[gn];
      int h = gn >> 6, d = gn & 63;
      if (z == 2) {
        int b = gm0 >> 10, n = gm0 & 1023;
        ushort4 pk;
#pragma unroll
        for (int r = 0; r < 4; r++) pk[r] = f2bf(acc[i][j][r] + bb);
        *(ushort4*)(&Vt[(((size_t)(b * 8 + h) * 64 + d) << 10) + n]) = pk;  // [bh][d][n]
      } else {
#pragma unroll
        for (int r = 0; r < 4; r++) {
          int m = gm0 + r;
          int b = m >> 10, n = m & 1023;
          O[((((size_t)(b * 8 + h)) << 10) + n) * 64 + d] = f2bf(acc[i][j][r] + bb);
        }
      }
    }
  }
}

// ---------------- output projection GEMM (bf16 A, fp32 out) ----------------
__global__ __launch_bounds__(256) void out_gemm(const unsigned short* __restrict__ A,
                                                const unsigned short* __restrict__ W,
                                                const float* __restrict__ bias,
                                                float* __restrict__ Out) {
  __shared__ __align__(16) short As[64 * 32];
  __shared__ __align__(16) short Bs[128 * 32];
  const int tid = threadIdx.x;
  const int lane = tid & 63;
  const int wave = tid >> 6;
  const int c = lane & 15;
  const int q = lane >> 4;
  const int m0 = blockIdx.x * 64;
  const int n0 = blockIdx.y * 128;
  const int wr = (wave >> 1) * 32;
  const int wc = (wave & 1) * 64;

  floatx4 acc[2][4];
#pragma unroll
  for (int i = 0; i < 2; i++)
#pragma unroll
    for (int j = 0; j < 4; j++) acc[i][j] = (floatx4)(0.0f);

  for (int k0 = 0; k0 < 512; k0 += 32) {
    __syncthreads();
    {
      int slot = wave * 64 + lane;
      int arow = slot >> 2, ach = slot & 3;
      int g = ach ^ xsw(arow);
      gload_lds16(A + (size_t)(m0 + arow) * 512 + k0 + g * 8, &As[(size_t)(wave * 64) * 8]);
    }
#pragma unroll
    for (int it = 0; it < 2; it++) {
      int slot = wave * 128 + it * 64 + lane;
      int brow = slot >> 2, bch = slot & 3;
      int g = bch ^ xsw(brow);
      gload_lds16(W + (size_t)(n0 + brow) * 512 + k0 + g * 8,
                  &Bs[(size_t)(wave * 128 + it * 64) * 8]);
    }
    __syncthreads();

    short8 af[2], bfv[4];
#pragma unroll
    for (int i = 0; i < 2; i++) {
      int row = wr + i * 16 + c;
      af[i] = *(const short8*)(&As[row * 32 + (q ^ xsw(row)) * 8]);
    }
#pragma unroll
    for (int j = 0; j < 4; j++) {
      int row = wc + j * 16 + c;
      bfv[j] = *(const short8*)(&Bs[row * 32 + (q ^ xsw(row)) * 8]);
    }
#pragma unroll
    for (int i = 0; i < 2; i++)
#pragma unroll
      for (int j = 0; j < 4; j++)
        acc[i][j] = MFMA16(af[i], bfv[j], acc[i][j]);
  }

#pragma unroll
  for (int i = 0; i < 2; i++) {
    int gm0 = m0 + wr + i * 16 + q * 4;
#pragma unroll
    for (int j = 0; j < 4; j++) {
      int gn = n0 + wc + j * 16 + c;
      float bb = bias[gn];
#pragma unroll
      for (int r = 0; r < 4; r++)
        Out[(size_t)(gm0 + r) * 512 + gn] = acc[i][j][r] + bb;
    }
  }
}

// ---------------- barrier-free flash attention (kt-split, swapped QK^T) ----
// Block (gx, bh): 64 q-rows of head (b,h). Wave w: wsub=w&1 picks the 32-row
// sub-block, whalf=w>>1 picks K-tiles [whalf*4, +4). Quarter-tiled K loop
// (32 cols at a time) keeps score liveness at s2[2][2]=16 regs.
// QK^T is computed SWAPPED: mfma(K,Q) -> C col = q-row (=c), C row = k
// ((lane>>4)*4+reg). Each lane thus holds 4 k-consecutive P values per
// (st,ci): 2x v_cvt_pk_bf16_f32 + 1 ds_write_b64 replace 4 f2bf sequences +
// 4 ds_write_b16. P lands row-major [q-row][k] exactly as the (proven
// conflict-free) PV b128 read expects. Row sums: 1 scalar/stripe/lane,
// reduced over the hi-groups with 2 shfl_xor at the end.
// kt-half partials merge by addition via one LDS round-trip (2 barriers).
__global__ __launch_bounds__(256, 3) void attn_kernel(const unsigned short* __restrict__ Qh,
                                                      const unsigned short* __restrict__ Kh,
                                                      const unsigned short* __restrict__ Vt,
                                                      const unsigned char* __restrict__ codesP,
                                                      unsigned short* __restrict__ AO) {
  __shared__ __align__(16) unsigned short P[4][32 * 132];   // 33 KB, wave-private regions
  const int tid = threadIdx.x;
  const int lane = tid & 63;
  const int wave = tid >> 6;
  const int wsub = wave & 1;     // which 32-row sub-block
  const int whalf = wave >> 1;   // which kt half
  const int c = lane & 15;
  const int q = lane >> 4;
  const int bh = blockIdx.y;
  const int b = bh >> 3;
  const int h = bh & 7;
  const size_t base = (size_t)bh << 16;
  const int rbase = blockIdx.x * 64 + wsub * 32;
  const int rg = rbase >> 5;
  unsigned short* Pw = &P[wave][0];

  // Q A-fragments for both 16-row stripes, held all kernel
  short8 aq[2][2];
#pragma unroll
  for (int st = 0; st < 2; st++)
#pragma unroll
    for (int kk = 0; kk < 2; kk++)
      aq[st][kk] = *(const short8*)(Qh + base + (size_t)(rbase + st * 16 + c) * 64 + kk * 32 + q * 8);

  const unsigned char* cbt = codesP + (size_t)(b * 32 + rg) * 32768 + lane * 64;
  const unsigned short* Kb = Kh + base;
  const unsigned short* Vb = Vt + base;

  float rsum[2] = {0.0f, 0.0f};
  floatx4 o[2][4];
#pragma unroll
  for (int st = 0; st < 2; st++)
#pragma unroll
    for (int ci = 0; ci < 4; ci++) o[st][ci] = (floatx4)(0.0f);

  for (int kti = 0; kti < 4; kti++) {
    const int kt = whalf * 4 + kti;
    const unsigned short* Kt = Kb + (size_t)kt * 128 * 64;
    const unsigned char* cp = cbt + (size_t)kt * 4096;
#pragma unroll
    for (int j = 0; j < 4; j++) {
      // ---- swapped QK^T quarter: ci = 2j, 2j+1; lane holds S[q=c][k] ----
      floatx4 s2[2][2];
      s2[0][0] = (floatx4)(0.0f); s2[0][1] = (floatx4)(0.0f);
      s2[1][0] = (floatx4)(0.0f); s2[1][1] = (floatx4)(0.0f);
#pragma unroll
      for (int u = 0; u < 2; u++) {
        int ci = 2 * j + u;
#pragma unroll
        for (int kk = 0; kk < 2; kk++) {
          short8 bk = *(const short8*)(Kt + (size_t)(ci * 16 + c) * 64 + kk * 32 + q * 8);
          s2[0][u] = MFMA16(bk, aq[0][kk], s2[0][u]);
          s2[1][u] = MFMA16(bk, aq[1][kk], s2[1][u]);
        }
      }
      // ---- codes for this quarter: 8 bytes per stripe, coalesced dwordx2 ----
      uint2 cw0 = *(const uint2*)(cp + j * 8);        // st=0: ci=2j r0..3, ci=2j+1 r0..3
      uint2 cw1 = *(const uint2*)(cp + 32 + j * 8);   // st=1
      // ---- exp -> cvt_pk -> b64 P write + scalar row sums ----
#pragma unroll
      for (int st = 0; st < 2; st++) {
#pragma unroll
        for (int u = 0; u < 2; u++) {
          unsigned w = st ? (u ? cw1.y : cw1.x) : (u ? cw0.y : cw0.x);
          float ev[4];
#pragma unroll
          for (int r = 0; r < 4; r++) {
            int code = (w >> (r * 8)) & 0xff;
            float ee = (h >= code) ? exp2f(s2[st][u][r] * 0.1803368801111362f) : 0.0f;
            rsum[st] += ee;
            ev[r] = ee;
          }
          unsigned p0, p1;
          asm("v_cvt_pk_bf16_f32 %0, %1, %2" : "=v"(p0) : "v"(ev[0]), "v"(ev[1]));
          asm("v_cvt_pk_bf16_f32 %0, %1, %2" : "=v"(p1) : "v"(ev[2]), "v"(ev[3]));
          uint2 pk; pk.x = p0; pk.y = p1;
          *(uint2*)(&Pw[(st * 16 + c) * 132 + (2 * j + u) * 16 + q * 4]) = pk;
        }
      }
      // ---- PV quarter: wave reads back its own P (lgkmcnt, no barrier) ----
      short8 ap0 = *(const short8*)(&Pw[(size_t)c * 132 + j * 32 + q * 8]);
      short8 ap1 = *(const short8*)(&Pw[(size_t)(16 + c) * 132 + j * 32 + q * 8]);
#pragma unroll
      for (int co = 0; co < 4; co++) {
        short8 bv = *(const short8*)(Vb + (size_t)(co * 16 + c) * 1024 + kt * 128 + j * 32 + q * 8);
        o[0][co] = MFMA16(ap0, bv, o[0][co]);
        o[1][co] = MFMA16(ap1, bv, o[1][co]);
      }
      __builtin_amdgcn_sched_barrier(0);   // cap liveness at quarter boundary
    }
  }

  // ---- merge kt-half partials: waves 2,3 -> LDS, waves 0,1 accumulate ----
  // chunks 0..7 = o[st][ci] (float4), chunk 8 = rsum[0..1] (float2). 18 KB.
  float* Pf = (float*)&P[0][0];
  __syncthreads();
  if (whalf == 1) {
#pragma unroll
    for (int st = 0; st < 2; st++)
#pragma unroll
      for (int ci = 0; ci < 4; ci++)
        *(floatx4*)&Pf[(((wsub * 9 + st * 4 + ci) * 64) + lane) * 4] = o[st][ci];
    float2 rr; rr.x = rsum[0]; rr.y = rsum[1];
    *(float2*)&Pf[(((wsub * 9 + 8) * 64) + lane) * 4] = rr;
  }
  __syncthreads();
  if (whalf == 1) return;

#pragma unroll
  for (int st = 0; st < 2; st++)
#pragma unroll
    for (int ci = 0; ci < 4; ci++) {
      floatx4 p = *(const floatx4*)&Pf[(((wsub * 9 + st * 4 + ci) * 64) + lane) * 4];
      o[st][ci] += p;
    }
  {
    float2 pr = *(const float2*)&Pf[(((wsub * 9 + 8) * 64) + lane) * 4];
    rsum[0] += pr.x; rsum[1] += pr.y;
  }

  // ---- normalize + write ----
  // Full row sum for q-row st*16+c: reduce partials across the 4 hi-groups.
  float inv2[2];
#pragma unroll
  for (int st = 0; st < 2; st++) {
    float v = rsum[st];
    v += __shfl_xor(v, 16);
    v += __shfl_xor(v, 32);
    inv2[st] = 1.0f / v;
  }
  // redistribute: lane (c,q) stores rows q*4+r -> needs inv from lane c'=q*4+r
  const int sb = (lane & 48) + ((lane & 48) >> 2);
  float iv[2][4];
#pragma unroll
  for (int st = 0; st < 2; st++)
#pragma unroll
    for (int r = 0; r < 4; r++) iv[st][r] = __shfl(inv2[st], sb + r);

#pragma unroll
  for (int st = 0; st < 2; st++)
#pragma unroll
    for (int r = 0; r < 4; r++) {
      int n = rbase + st * 16 + q * 4 + r;
      size_t ob = ((size_t)((b << 10) + n)) * 512 + h * 64;
#pragma unroll
      for (int ci = 0; ci < 4; ci++)
        AO[ob + ci * 16 + c] = f2bf(o[st][ci][r] * iv[st][r]);
    }
}

// ---------------- launcher ----------------
extern "C" void kernel_launch(void* const* d_in, const int* in_sizes, int n_in,
                              void* d_out, int out_size, void* d_ws, size_t ws_size,
                              hipStream_t stream) {
  const float* query = (const float*)d_in[0];
  const float* key_  = (const float*)d_in[1];
  const float* value = (const float*)d_in[2];
  const float* dist  = (const float*)d_in[3];
  const int*   mask  = (const int*)d_in[4];
  const float* Wq = (const float*)d_in[5];
  const float* bq = (const float*)d_in[6];
  const float* Wk = (const float*)d_in[7];
  const float* bk = (const float*)d_in[8];
  const float* Wv = (const float*)d_in[9];
  const float* bv = (const float*)d_in[10];
  const float* Wo = (const float*)d_in[11];
  const float* bo = (const float*)d_in[12];

  char* ws = (char*)d_ws;
  size_t off = 0;
  auto alloc = [&](size_t bytes) -> char* {
    char* p = ws + off;
    off += (bytes + 255) & ~(size_t)255;
    return p;
  };
  const size_t NQKV = 8192ull * 512;
  unsigned short* wq16 = (unsigned short*)alloc(512ull * 512 * 2);
  unsigned short* wk16 = (unsigned short*)alloc(512ull * 512 * 2);
  unsigned short* wv16 = (unsigned short*)alloc(512ull * 512 * 2);
  unsigned short* wo16 = (unsigned short*)alloc(512ull * 512 * 2);
  unsigned short* Qh = (unsigned short*)alloc(NQKV * 2);
  unsigned short* Kh = (unsigned short*)alloc(NQKV * 2);
  unsigned short* Vt = (unsigned short*)alloc(NQKV * 2);
  unsigned short* AO = (unsigned short*)alloc(NQKV * 2);
  unsigned char*  codesP = (unsigned char*)alloc(8ull * 1024 * 1024);

  wcast_kernel<<<1024, 256, 0, stream>>>(Wq, Wk, Wv, Wo, wq16, wk16, wv16, wo16);
  codes_kernel<<<8192, 256, 0, stream>>>(dist, mask, codesP);
  qkv_gemm<<<dim3(128, 4, 3), 256, 0, stream>>>(query, key_, value, wq16, wk16, wv16,
                                                bq, bk, bv, Qh, Kh, Vt);
  attn_kernel<<<dim3(16, 64), 256, 0, stream>>>(Qh, Kh, Vt, codesP, AO);
  out_gemm<<<dim3(128, 4), 256, 0, stream>>>(AO, wo16, bo, (float*)d_out);
}

// Round 6
// 281.032 us; speedup vs baseline: 1.0971x; 1.0071x over previous
//
#include <hip/hip_runtime.h>
#include <stdint.h>

// ---------------------------------------------------------------------------
// MultiHeadedAttention: B=8, N=1024, E=512, H=8, D_K=64
// bf16 MFMA pipeline. Round 9: software-pipelined phases. (kt,quarter)
// flattened into 16 phases; V loads issue at phase top (consumed at bottom),
// K fragments are prefetched one phase ahead (issued right after the MFMAs
// that consume the previous set). Exactly one sched_barrier(0) per phase
// (between P-write and P-read) pins the pipeline and bounds liveness.
// Exposed per-phase latency drops from ~850cy (K-load + LDS-RT + V-load)
// to ~350cy (LDS-RT + ALU only). Swapped-QK^T epilogue retained from R8.
// ---------------------------------------------------------------------------

typedef __attribute__((ext_vector_type(8))) short short8;
typedef __attribute__((ext_vector_type(4))) float floatx4;

#define MFMA16(a, b, c) __builtin_amdgcn_mfma_f32_16x16x32_bf16((a), (b), (c), 0, 0, 0)

static __device__ __forceinline__ unsigned short f2bf(float f) {
  union { float f; unsigned u; } v; v.f = f;
  unsigned r = v.u + 0x7fffu + ((v.u >> 16) & 1u);   // RNE
  return (unsigned short)(r >> 16);
}

// async global->LDS 16B/lane. LDS dest is wave-uniform base + lane*16 (m104).
static __device__ __forceinline__ void gload_lds16(const void* g, void* l) {
  __builtin_amdgcn_global_load_lds((const __attribute__((address_space(1))) unsigned int*)g,
                                   (__attribute__((address_space(3))) unsigned int*)l,
                                   16, 0, 0);
}
// chunk swizzle for unpadded 32-elem-wide bf16 LDS tiles (GEMM staging).
static __device__ __forceinline__ int xsw(int row) { return (row & 3) ^ ((row >> 2) & 3); }

// ---------------- weight cast fp32 -> bf16 (all 4 at once) ----------------
__global__ void wcast_kernel(const float* __restrict__ Wq, const float* __restrict__ Wk,
                             const float* __restrict__ Wv, const float* __restrict__ Wo,
                             unsigned short* __restrict__ o0, unsigned short* __restrict__ o1,
                             unsigned short* __restrict__ o2, unsigned short* __restrict__ o3) {
  int i = blockIdx.x * blockDim.x + threadIdx.x;   // 0..262143
  int w = i >> 16, loc = i & 65535;
  const float* s = (w == 0) ? Wq : (w == 1) ? Wk : (w == 2) ? Wv : Wo;
  unsigned short* d = (w == 0) ? o0 : (w == 1) ? o1 : (w == 2) ? o2 : o3;
  float4 v = ((const float4*)s)[loc];
  ushort4 o;
  o.x = f2bf(v.x); o.y = f2bf(v.y); o.z = f2bf(v.z); o.w = f2bf(v.w);
  ((ushort4*)d)[loc] = o;
}

// ---------------- dist+mask -> permuted code bytes ----------------
// allowed(h) <=> h >= code (DIST_BAR ascending). 0 on row/col 0; 9 if mask==0.
// Layout matches the SWAPPED-QK^T attn epilogue: element
//   (q-row = rg*32 + st*16 + c, k-col = kt*128 + ci*16 + hi*4 + r)
// is held by attn lane = hi*16 + c and read at byte st*32 + ci*4 + r of that
// lane's 64-byte block:
//   codesP[ (((b*32+rg)*8 + kt)*64 + lane)*64 + st*32 + ci*4 + r ]
// Each thread here covers 4 consecutive cols (same ci,hi; r=0..3) -> one
// packed u32 store.
__global__ void codes_kernel(const float* __restrict__ dist, const int* __restrict__ mask,
                             unsigned char* __restrict__ codesP) {
  int t = blockIdx.x * blockDim.x + threadIdx.x;   // over B*N*N/4
  int flat = t << 2;
  int b = flat >> 20;
  int rem = flat & ((1 << 20) - 1);
  int row = rem >> 10;
  int col0 = rem & 1023;                            // multiple of 4
  float4 d4 = ((const float4*)dist)[t];
  int4 m4 = ((const int4*)mask)[t];
  float dv[4] = {d4.x, d4.y, d4.z, d4.w};
  int mv[4] = {m4.x, m4.y, m4.z, m4.w};
  int rg = row >> 5;
  int st = (row >> 4) & 1;
  int c = row & 15;
  size_t rowbase = (size_t)(b * 32 + rg) * 32768;   // *8 kt *4096
  int kt = col0 >> 7;
  int colk = col0 & 127;
  int ci = colk >> 4;
  int hi = (colk >> 2) & 3;
  int lane = hi * 16 + c;
  unsigned pack = 0;
#pragma unroll
  for (int u = 0; u < 4; u++) {
    int col = col0 + u;
    float d = dv[u];
    int hmin = (d >= 0.2f) + (d >= 0.3f) + (d >= 0.4f) + (d >= 0.5f) +
               (d >= 0.6f) + (d >= 0.7f) + (d >= 0.8f) + (d >= 0.9f);
    unsigned cc = (unsigned)hmin;
    if (row == 0 || col == 0) cc = 0;
    if (mv[u] == 0) cc = 9;
    pack |= cc << (u * 8);
  }
  *(unsigned*)&codesP[rowbase + (size_t)kt * 4096 + lane * 64 + st * 32 + ci * 4] = pack;
}

// ---------------- fused QKV projection GEMM ----------------
// C[m][n] = sum_k A[m][k] * W[n][k] + bias[n];  M=8192, N=512, K=512.
// 64x128 tile, 4 waves. A fp32 (cast fused). z=0/1: [bh][n][d]; z=2: [bh][d][n].
__global__ __launch_bounds__(256) void qkv_gemm(
    const float* __restrict__ Aq, const float* __restrict__ Ak, const float* __restrict__ Av,
    const unsigned short* __restrict__ Wqp, const unsigned short* __restrict__ Wkp,
    const unsigned short* __restrict__ Wvp,
    const float* __restrict__ bq, const float* __restrict__ bk, const float* __restrict__ bv,
    unsigned short* __restrict__ Qh, unsigned short* __restrict__ Kh,
    unsigned short* __restrict__ Vt) {
  const int z = blockIdx.z;
  const float* A = (z == 0) ? Aq : (z == 1) ? Ak : Av;
  const unsigned short* W = (z == 0) ? Wqp : (z == 1) ? Wkp : Wvp;
  const float* bias = (z == 0) ? bq : (z == 1) ? bk : bv;
  unsigned short* O = (z == 0) ? Qh : (z == 1) ? Kh : Vt;

  __shared__ __align__(16) short As[64 * 40];
  __shared__ __align__(16) short Bs[128 * 32];
  const int tid = threadIdx.x;
  const int lane = tid & 63;
  const int wave = tid >> 6;
  const int c = lane & 15;
  const int q = lane >> 4;
  const int m0 = blockIdx.x * 64;
  const int n0 = blockIdx.y * 128;
  const int wr = (wave >> 1) * 32;
  const int wc = (wave & 1) * 64;

  floatx4 acc[2][4];
#pragma unroll
  for (int i = 0; i < 2; i++)
#pragma unroll
    for (int j = 0; j < 4; j++) acc[i][j] = (floatx4)(0.0f);

  const int arow = tid >> 2, ach = tid & 3;
  const float* Ab = A + (size_t)(m0 + arow) * 512 + ach * 8;

  for (int k0 = 0; k0 < 512; k0 += 32) {
    __syncthreads();
#pragma unroll
    for (int it = 0; it < 2; it++) {
      int slot = wave * 128 + it * 64 + lane;
      int brow = slot >> 2, bch = slot & 3;
      int g = bch ^ xsw(brow);
      gload_lds16(W + (size_t)(n0 + brow) * 512 + k0 + g * 8,
                  &Bs[(size_t)(wave * 128 + it * 64) * 8]);
    }
    float4 a0 = *(const float4*)(Ab + k0);
    float4 a1 = *(const float4*)(Ab + k0 + 4);
    short8 av;
    av[0] = (short)f2bf(a0.x); av[1] = (short)f2bf(a0.y);
    av[2] = (short)f2bf(a0.z); av[3] = (short)f2bf(a0.w);
    av[4] = (short)f2bf(a1.x); av[5] = (short)f2bf(a1.y);
    av[6] = (short)f2bf(a1.z); av[7] = (short)f2bf(a1.w);
    *(short8*)(&As[arow * 40 + ach * 8]) = av;
    __syncthreads();

    short8 af[2], bfv[4];
#pragma unroll
    for (int i = 0; i < 2; i++)
      af[i] = *(const short8*)(&As[(wr + i * 16 + c) * 40 + q * 8]);
#pragma unroll
    for (int j = 0; j < 4; j++) {
      int row = wc + j * 16 + c;
      bfv[j] = *(const short8*)(&Bs[row * 32 + (q ^ xsw(row)) * 8]);
    }
#pragma unroll
    for (int i = 0; i < 2; i++)
#pragma unroll
      for (int j = 0; j < 4; j++)
        acc[i][j] = MFMA16(af[i], bfv[j], acc[i][j]);
  }

#pragma unroll
  for (int i = 0; i < 2; i++) {
    int gm0 = m0 + wr + i * 16 + q * 4;
#pragma unroll
    for (int j = 0; j < 4; j++) {
      int gn = n0 + wc + j * 16 + c;
      float bb = bias[gn];
      int h = gn >> 6, d = gn & 63;
      if (z == 2) {
        int b = gm0 >> 10, n = gm0 & 1023;
        ushort4 pk;
#pragma unroll
        for (int r = 0; r < 4; r++) pk[r] = f2bf(acc[i][j][r] + bb);
        *(ushort4*)(&Vt[(((size_t)(b * 8 + h) * 64 + d) << 10) + n]) = pk;  // [bh][d][n]
      } else {
#pragma unroll
        for (int r = 0; r < 4; r++) {
          int m = gm0 + r;
          int b = m >> 10, n = m & 1023;
          O[((((size_t)(b * 8 + h)) << 10) + n) * 64 + d] = f2bf(acc[i][j][r] + bb);
        }
      }
    }
  }
}

// ---------------- output projection GEMM (bf16 A, fp32 out) ----------------
__global__ __launch_bounds__(256) void out_gemm(const unsigned short* __restrict__ A,
                                                const unsigned short* __restrict__ W,
                                                const float* __restrict__ bias,
                                                float* __restrict__ Out) {
  __shared__ __align__(16) short As[64 * 32];
  __shared__ __align__(16) short Bs[128 * 32];
  const int tid = threadIdx.x;
  const int lane = tid & 63;
  const int wave = tid >> 6;
  const int c = lane & 15;
  const int q = lane >> 4;
  const int m0 = blockIdx.x * 64;
  const int n0 = blockIdx.y * 128;
  const int wr = (wave >> 1) * 32;
  const int wc = (wave & 1) * 64;

  floatx4 acc[2][4];
#pragma unroll
  for (int i = 0; i < 2; i++)
#pragma unroll
    for (int j = 0; j < 4; j++) acc[i][j] = (floatx4)(0.0f);

  for (int k0 = 0; k0 < 512; k0 += 32) {
    __syncthreads();
    {
      int slot = wave * 64 + lane;
      int arow = slot >> 2, ach = slot & 3;
      int g = ach ^ xsw(arow);
      gload_lds16(A + (size_t)(m0 + arow) * 512 + k0 + g * 8, &As[(size_t)(wave * 64) * 8]);
    }
#pragma unroll
    for (int it = 0; it < 2; it++) {
      int slot = wave * 128 + it * 64 + lane;
      int brow = slot >> 2, bch = slot & 3;
      int g = bch ^ xsw(brow);
      gload_lds16(W + (size_t)(n0 + brow) * 512 + k0 + g * 8,
                  &Bs[(size_t)(wave * 128 + it * 64) * 8]);
    }
    __syncthreads();

    short8 af[2], bfv[4];
#pragma unroll
    for (int i = 0; i < 2; i++) {
      int row = wr + i * 16 + c;
      af[i] = *(const short8*)(&As[row * 32 + (q ^ xsw(row)) * 8]);
    }
#pragma unroll
    for (int j = 0; j < 4; j++) {
      int row = wc + j * 16 + c;
      bfv[j] = *(const short8*)(&Bs[row * 32 + (q ^ xsw(row)) * 8]);
    }
#pragma unroll
    for (int i = 0; i < 2; i++)
#pragma unroll
      for (int j = 0; j < 4; j++)
        acc[i][j] = MFMA16(af[i], bfv[j], acc[i][j]);
  }

#pragma unroll
  for (int i = 0; i < 2; i++) {
    int gm0 = m0 + wr + i * 16 + q * 4;
#pragma unroll
    for (int j = 0; j < 4; j++) {
      int gn = n0 + wc + j * 16 + c;
      float bb = bias[gn];
#pragma unroll
      for (int r = 0; r < 4; r++)
        Out[(size_t)(gm0 + r) * 512 + gn] = acc[i][j][r] + bb;
    }
  }
}

// ---------------- software-pipelined flash attention (kt-split) ----------
// Block (gx, bh): 64 q-rows of head (b,h). Wave w: wsub=w&1 picks the 32-row
// sub-block, whalf=w>>1 picks K-tiles [whalf*4, +4). (kt,quarter) flattened
// into 16 phases. Per phase:
//   top:    issue V loads (4 b128) + codes loads   [consumed at bottom]
//   QK^T:   8 swapped MFMAs on K frags PREFETCHED last phase (no load wait)
//   then:   issue next phase's K loads (hidden under exp+P-RT+PV)
//   exp:    mask/exp2 + cvt_pk -> 4 ds_write_b64 to wave-private P
//   sched_barrier(0)   <- one per phase: pins pipeline, bounds hoisting
//   PV:     2 ds_read_b128 (lgkm) + 8 MFMAs on the resident V frags
// Only the LDS P round-trip latency remains on the chain; all global-load
// latency is overlapped. launch_bounds (256,3): 170-reg budget, ~150 used.
// kt-half partials merge by addition via one LDS round-trip (2 barriers).
__global__ __launch_bounds__(256, 3) void attn_kernel(const unsigned short* __restrict__ Qh,
                                                      const unsigned short* __restrict__ Kh,
                                                      const unsigned short* __restrict__ Vt,
                                                      const unsigned char* __restrict__ codesP,
                                                      unsigned short* __restrict__ AO) {
  __shared__ __align__(16) unsigned short P[4][32 * 132];   // 33 KB, wave-private regions
  const int tid = threadIdx.x;
  const int lane = tid & 63;
  const int wave = tid >> 6;
  const int wsub = wave & 1;     // which 32-row sub-block
  const int whalf = wave >> 1;   // which kt half
  const int c = lane & 15;
  const int q = lane >> 4;
  const int bh = blockIdx.y;
  const int b = bh >> 3;
  const int h = bh & 7;
  const size_t base = (size_t)bh << 16;
  const int rbase = blockIdx.x * 64 + wsub * 32;
  const int rg = rbase >> 5;
  unsigned short* Pw = &P[wave][0];

  // Q A-fragments for both 16-row stripes, held all kernel
  short8 aq[2][2];
#pragma unroll
  for (int st = 0; st < 2; st++)
#pragma unroll
    for (int kk = 0; kk < 2; kk++)
      aq[st][kk] = *(const short8*)(Qh + base + (size_t)(rbase + st * 16 + c) * 64 + kk * 32 + q * 8);

  const unsigned char* cbt = codesP + (size_t)(b * 32 + rg) * 32768 + lane * 64;
  const unsigned short* Kb = Kh + base;
  const unsigned short* Vb = Vt + base;

  float rsum[2] = {0.0f, 0.0f};
  floatx4 o[2][4];
#pragma unroll
  for (int st = 0; st < 2; st++)
#pragma unroll
    for (int ci = 0; ci < 4; ci++) o[st][ci] = (floatx4)(0.0f);

  // ---- prologue: prefetch K fragments for phase 0 (kt=whalf*4, j=0) ----
  short8 bk00, bk01, bk10, bk11;   // [u][kk], u: ci=2j+u
  {
    const unsigned short* Kt0 = Kb + (size_t)(whalf * 4) * 8192;
    bk00 = *(const short8*)(Kt0 + (size_t)(0 * 16 + c) * 64 + 0 * 32 + q * 8);
    bk01 = *(const short8*)(Kt0 + (size_t)(0 * 16 + c) * 64 + 1 * 32 + q * 8);
    bk10 = *(const short8*)(Kt0 + (size_t)(1 * 16 + c) * 64 + 0 * 32 + q * 8);
    bk11 = *(const short8*)(Kt0 + (size_t)(1 * 16 + c) * 64 + 1 * 32 + q * 8);
  }

#pragma unroll
  for (int ph = 0; ph < 16; ph++) {
    const int kt = whalf * 4 + (ph >> 2);
    const int j = ph & 3;
    const unsigned char* cp = cbt + (size_t)kt * 4096;

    // ---- top: V loads for THIS phase (consumed by PV at the bottom) ----
    short8 vv0 = *(const short8*)(Vb + (size_t)(0 * 16 + c) * 1024 + kt * 128 + j * 32 + q * 8);
    short8 vv1 = *(const short8*)(Vb + (size_t)(1 * 16 + c) * 1024 + kt * 128 + j * 32 + q * 8);
    short8 vv2 = *(const short8*)(Vb + (size_t)(2 * 16 + c) * 1024 + kt * 128 + j * 32 + q * 8);
    short8 vv3 = *(const short8*)(Vb + (size_t)(3 * 16 + c) * 1024 + kt * 128 + j * 32 + q * 8);
    uint2 cw0 = *(const uint2*)(cp + j * 8);        // st=0 codes
    uint2 cw1 = *(const uint2*)(cp + 32 + j * 8);   // st=1 codes

    // ---- swapped QK^T on prefetched K: lane holds S[q=c][k] ----
    floatx4 s2[2][2];
    s2[0][0] = (floatx4)(0.0f); s2[0][1] = (floatx4)(0.0f);
    s2[1][0] = (floatx4)(0.0f); s2[1][1] = (floatx4)(0.0f);
    s2[0][0] = MFMA16(bk00, aq[0][0], s2[0][0]);
    s2[1][0] = MFMA16(bk00, aq[1][0], s2[1][0]);
    s2[0][0] = MFMA16(bk01, aq[0][1], s2[0][0]);
    s2[1][0] = MFMA16(bk01, aq[1][1], s2[1][0]);
    s2[0][1] = MFMA16(bk10, aq[0][0], s2[0][1]);
    s2[1][1] = MFMA16(bk10, aq[1][0], s2[1][1]);
    s2[0][1] = MFMA16(bk11, aq[0][1], s2[0][1]);
    s2[1][1] = MFMA16(bk11, aq[1][1], s2[1][1]);

    // ---- prefetch K for the NEXT phase (WAR on bk regs is issue-safe) ----
    if (ph < 15) {
      const int phn = ph + 1;
      const int ktn = whalf * 4 + (phn >> 2);
      const int jn = phn & 3;
      const unsigned short* Ktn = Kb + (size_t)ktn * 8192;
      bk00 = *(const short8*)(Ktn + (size_t)((2 * jn + 0) * 16 + c) * 64 + 0 * 32 + q * 8);
      bk01 = *(const short8*)(Ktn + (size_t)((2 * jn + 0) * 16 + c) * 64 + 1 * 32 + q * 8);
      bk10 = *(const short8*)(Ktn + (size_t)((2 * jn + 1) * 16 + c) * 64 + 0 * 32 + q * 8);
      bk11 = *(const short8*)(Ktn + (size_t)((2 * jn + 1) * 16 + c) * 64 + 1 * 32 + q * 8);
    }

    // ---- exp -> cvt_pk -> b64 P write + scalar row sums ----
#pragma unroll
    for (int st = 0; st < 2; st++) {
#pragma unroll
      for (int u = 0; u < 2; u++) {
        unsigned w = st ? (u ? cw1.y : cw1.x) : (u ? cw0.y : cw0.x);
        float ev[4];
#pragma unroll
        for (int r = 0; r < 4; r++) {
          int code = (w >> (r * 8)) & 0xff;
          float ee = (h >= code) ? exp2f(s2[st][u][r] * 0.1803368801111362f) : 0.0f;
          rsum[st] += ee;
          ev[r] = ee;
        }
        unsigned p0, p1;
        asm("v_cvt_pk_bf16_f32 %0, %1, %2" : "=v"(p0) : "v"(ev[0]), "v"(ev[1]));
        asm("v_cvt_pk_bf16_f32 %0, %1, %2" : "=v"(p1) : "v"(ev[2]), "v"(ev[3]));
        uint2 pk; pk.x = p0; pk.y = p1;
        *(uint2*)(&Pw[(st * 16 + c) * 132 + (2 * j + u) * 16 + q * 4]) = pk;
      }
    }

    __builtin_amdgcn_sched_barrier(0);   // phase waist: write side || read side

    // ---- PV: read back own P (lgkm) x resident V frags ----
    short8 ap0 = *(const short8*)(&Pw[(size_t)c * 132 + j * 32 + q * 8]);
    short8 ap1 = *(const short8*)(&Pw[(size_t)(16 + c) * 132 + j * 32 + q * 8]);
    o[0][0] = MFMA16(ap0, vv0, o[0][0]);
    o[1][0] = MFMA16(ap1, vv0, o[1][0]);
    o[0][1] = MFMA16(ap0, vv1, o[0][1]);
    o[1][1] = MFMA16(ap1, vv1, o[1][1]);
    o[0][2] = MFMA16(ap0, vv2, o[0][2]);
    o[1][2] = MFMA16(ap1, vv2, o[1][2]);
    o[0][3] = MFMA16(ap0, vv3, o[0][3]);
    o[1][3] = MFMA16(ap1, vv3, o[1][3]);
  }

  // ---- merge kt-half partials: waves 2,3 -> LDS, waves 0,1 accumulate ----
  // chunks 0..7 = o[st][ci] (float4), chunk 8 = rsum[0..1] (float2). 18 KB.
  float* Pf = (float*)&P[0][0];
  __syncthreads();
  if (whalf == 1) {
#pragma unroll
    for (int st = 0; st < 2; st++)
#pragma unroll
      for (int ci = 0; ci < 4; ci++)
        *(floatx4*)&Pf[(((wsub * 9 + st * 4 + ci) * 64) + lane) * 4] = o[st][ci];
    float2 rr; rr.x = rsum[0]; rr.y = rsum[1];
    *(float2*)&Pf[(((wsub * 9 + 8) * 64) + lane) * 4] = rr;
  }
  __syncthreads();
  if (whalf == 1) return;

#pragma unroll
  for (int st = 0; st < 2; st++)
#pragma unroll
    for (int ci = 0; ci < 4; ci++) {
      floatx4 p = *(const floatx4*)&Pf[(((wsub * 9 + st * 4 + ci) * 64) + lane) * 4];
      o[st][ci] += p;
    }
  {
    float2 pr = *(const float2*)&Pf[(((wsub * 9 + 8) * 64) + lane) * 4];
    rsum[0] += pr.x; rsum[1] += pr.y;
  }

  // ---- normalize + write ----
  // Full row sum for q-row st*16+c: reduce partials across the 4 hi-groups.
  float inv2[2];
#pragma unroll
  for (int st = 0; st < 2; st++) {
    float v = rsum[st];
    v += __shfl_xor(v, 16);
    v += __shfl_xor(v, 32);
    inv2[st] = 1.0f / v;
  }
  // redistribute: lane (c,q) stores rows q*4+r -> needs inv from lane c'=q*4+r
  const int sb = (lane & 48) + ((lane & 48) >> 2);
  float iv[2][4];
#pragma unroll
  for (int st = 0; st < 2; st++)
#pragma unroll
    for (int r = 0; r < 4; r++) iv[st][r] = __shfl(inv2[st], sb + r);

#pragma unroll
  for (int st = 0; st < 2; st++)
#pragma unroll
    for (int r = 0; r < 4; r++) {
      int n = rbase + st * 16 + q * 4 + r;
      size_t ob = ((size_t)((b << 10) + n)) * 512 + h * 64;
#pragma unroll
      for (int ci = 0; ci < 4; ci++)
        AO[ob + ci * 16 + c] = f2bf(o[st][ci][r] * iv[st][r]);
    }
}

// ---------------- launcher ----------------
extern "C" void kernel_launch(void* const* d_in, const int* in_sizes, int n_in,
                              void* d_out, int out_size, void* d_ws, size_t ws_size,
                              hipStream_t stream) {
  const float* query = (const float*)d_in[0];
  const float* key_  = (const float*)d_in[1];
  const float* value = (const float*)d_in[2];
  const float* dist  = (const float*)d_in[3];
  const int*   mask  = (const int*)d_in[4];
  const float* Wq = (const float*)d_in[5];
  const float* bq = (const float*)d_in[6];
  const float* Wk = (const float*)d_in[7];
  const float* bk = (const float*)d_in[8];
  const float* Wv = (const float*)d_in[9];
  const float* bv = (const float*)d_in[10];
  const float* Wo = (const float*)d_in[11];
  const float* bo = (const float*)d_in[12];

  char* ws = (char*)d_ws;
  size_t off = 0;
  auto alloc = [&](size_t bytes) -> char* {
    char* p = ws + off;
    off += (bytes + 255) & ~(size_t)255;
    return p;
  };
  const size_t NQKV = 8192ull * 512;
  unsigned short* wq16 = (unsigned short*)alloc(512ull * 512 * 2);
  unsigned short* wk16 = (unsigned short*)alloc(512ull * 512 * 2);
  unsigned short* wv16 = (unsigned short*)alloc(512ull * 512 * 2);
  unsigned short* wo16 = (unsigned short*)alloc(512ull * 512 * 2);
  unsigned short* Qh = (unsigned short*)alloc(NQKV * 2);
  unsigned short* Kh = (unsigned short*)alloc(NQKV * 2);
  unsigned short* Vt = (unsigned short*)alloc(NQKV * 2);
  unsigned short* AO = (unsigned short*)alloc(NQKV * 2);
  unsigned char*  codesP = (unsigned char*)alloc(8ull * 1024 * 1024);

  wcast_kernel<<<1024, 256, 0, stream>>>(Wq, Wk, Wv, Wo, wq16, wk16, wv16, wo16);
  codes_kernel<<<8192, 256, 0, stream>>>(dist, mask, codesP);
  qkv_gemm<<<dim3(128, 4, 3), 256, 0, stream>>>(query, key_, value, wq16, wk16, wv16,
                                                bq, bk, bv, Qh, Kh, Vt);
  attn_kernel<<<dim3(16, 64), 256, 0, stream>>>(Qh, Kh, Vt, codesP, AO);
  out_gemm<<<dim3(128, 4), 256, 0, stream>>>(AO, wo16, bo, (float*)d_out);
}